// Round 13
// baseline (8772.842 us; speedup 1.0000x reference)
//
#include <hip/hip_runtime.h>
#include <hip/hip_fp16.h>
#include <stdint.h>

#define B_ 64
#define T_ 2048
#define I_ 16
#define H_ 256
#define G_ 768   // 3*H

// dynamic LDS: 18 weight slabs thread-major (147456) + hq[2][2][2][17] u32x4 (8704)
#define REC_SMEM 156160

typedef _Float16 f16;
typedef _Float16 half2_t __attribute__((ext_vector_type(2)));
typedef uint32_t u32x4 __attribute__((ext_vector_type(4)));
typedef uint32_t u32x2 __attribute__((ext_vector_type(2)));

// ---------- fast math helpers ----------
__device__ __forceinline__ float fast_rcp(float x) {
#if __has_builtin(__builtin_amdgcn_rcpf)
    return __builtin_amdgcn_rcpf(x);
#else
    return 1.0f / x;
#endif
}
__device__ __forceinline__ float sigmoid_f(float x) {
    return fast_rcp(1.0f + __expf(-x));
}
__device__ __forceinline__ float tanh_f(float x) {
    float e = __expf(2.0f * x);
    return 1.0f - 2.0f * fast_rcp(e + 1.0f);
}

__device__ __forceinline__ float fdot2(uint32_t a, uint32_t b, float c) {
#if __has_builtin(__builtin_amdgcn_fdot2)
    return __builtin_amdgcn_fdot2(__builtin_bit_cast(half2_t, a),
                                  __builtin_bit_cast(half2_t, b), c, false);
#else
    half2_t ha = __builtin_bit_cast(half2_t, a), hb = __builtin_bit_cast(half2_t, b);
    return c + (float)ha.x * (float)hb.x + (float)ha.y * (float)hb.y;
#endif
}
__device__ __forceinline__ float dot_u4(u32x4 w, u32x4 h, float acc) {
    acc = fdot2(w.x, h.x, acc);
    acc = fdot2(w.y, h.y, acc);
    acc = fdot2(w.z, h.z, acc);
    acc = fdot2(w.w, h.w, acc);
    return acc;
}

// ---------- weight conversion (layout identical to R12) ----------
// Per Whh layer (stride 81920 dwords; L0 at 0, L1 at 81920):
//   [0,65536): 32 fp16 planes thread-major. u32x4 idx = P*512 + tid, tid=2j+hf.
//     P<16: z gate (row 256+j), u=P.  P>=16: n gate (row 512+j), u=P-16.
//   [65536,81920): 16 fp8-e5m2 r planes. u32x2 idx = P8*512 + tid.
// [163840,262144) Wih1T k-major fp16 | [262144,294912) W1T k-major fp16
__global__ __launch_bounds__(256) void cvt_weights(const float* __restrict__ whh0,
                                                   const float* __restrict__ whh1,
                                                   const float* __restrict__ wih1,
                                                   const float* __restrict__ w1,
                                                   uint32_t* __restrict__ out) {
    int idx = blockIdx.x * 256 + threadIdx.x;
    if (idx >= 294912) return;
    if (idx < 163840) {
        const float* w = (idx < 81920) ? whh0 : whh1;
        int l = (idx < 81920) ? idx : idx - 81920;
        if (l < 65536) {
            int u4 = l >> 2, d = l & 3;
            int P = u4 >> 9, t = u4 & 511;
            int j = t >> 1, hf = t & 1;
            int row = (P < 16) ? (256 + j) : (512 + j);
            int u = (P < 16) ? P : P - 16;
            const float* s = w + (size_t)row * 256 + hf * 128 + u * 8 + d * 2;
            half2_t h;
            h.x = (f16)s[0];
            h.y = (f16)s[1];
            out[idx] = __builtin_bit_cast(uint32_t, h);
        } else {
            int l2 = l - 65536;
            int P8 = l2 >> 10, wd = l2 & 1023;
            int t = wd >> 1, piece = wd & 1;
            int j = t >> 1, hf = t & 1;
            const float* s = w + (size_t)j * 256 + hf * 128 + P8 * 8 + piece * 4;
            uint32_t dw = 0;
            #pragma unroll
            for (int k = 0; k < 4; ++k) {
                f16 hh = (f16)s[k];
                uint16_t hb = __builtin_bit_cast(uint16_t, hh);
                uint16_t r8 = (uint16_t)((hb + 0x7F + ((hb >> 8) & 1)) >> 8); // RN to e5m2
                dw |= (uint32_t)(r8 & 0xFF) << (8 * k);
            }
            out[idx] = dw;
        }
    } else if (idx < 262144) {
        int local = idx - 163840;
        int u4 = local >> 2, d = local & 3;
        int k8 = u4 / 768, g = u4 - k8 * 768;
        const float* s = wih1 + (size_t)g * 256 + k8 * 8 + d * 2;
        half2_t h; h.x = (f16)s[0]; h.y = (f16)s[1];
        out[idx] = __builtin_bit_cast(uint32_t, h);
    } else {
        int local = idx - 262144;
        int u4 = local >> 2, d = local & 3;
        int k8 = u4 >> 8, g = u4 & 255;
        const float* s = w1 + (size_t)g * 256 + k8 * 8 + d * 2;
        half2_t h; h.x = (f16)s[0]; h.y = (f16)s[1];
        out[idx] = __builtin_bit_cast(uint32_t, h);
    }
}

// =======================================================================
// role bodies (512 threads each)
// =======================================================================

__device__ __forceinline__ void xg0_body(const float* __restrict__ x,
        const float* __restrict__ wih0, const float* __restrict__ bih0,
        float* __restrict__ xg, int t0, int C, int blk, char* smem) {
    float (*xs)[16] = (float(*)[16])smem;
    int tid = threadIdx.x;
    int m0 = blk * 64;
    if (tid < 256) {
        int r = tid >> 2, c4 = (tid & 3) * 4;
        int m = m0 + r;
        int b = m / C, tl = m - b * C;
        float4 v = *(const float4*)(x + (size_t)(b * T_ + t0 + tl) * I_ + c4);
        *(float4*)&xs[r][c4] = v;
    }
    __syncthreads();
    for (int g = tid; g < G_; g += 512) {
        const float4* wr = (const float4*)(wih0 + (size_t)g * I_);
        float4 w0 = wr[0], w1 = wr[1], w2 = wr[2], w3 = wr[3];
        float bias = bih0[g];
        float* outp = xg + (size_t)m0 * G_ + g;
        for (int m = 0; m < 64; ++m) {
            const float4* xr4 = (const float4*)xs[m];
            float4 a0 = xr4[0], a1 = xr4[1], a2 = xr4[2], a3 = xr4[3];
            float acc = bias;
            acc += a0.x*w0.x + a0.y*w0.y + a0.z*w0.z + a0.w*w0.w;
            acc += a1.x*w1.x + a1.y*w1.y + a1.z*w1.z + a1.w*w1.w;
            acc += a2.x*w2.x + a2.y*w2.y + a2.z*w2.z + a2.w*w2.w;
            acc += a3.x*w3.x + a3.y*w3.y + a3.z*w3.z + a3.w*w3.w;
            outp[(size_t)m * G_] = acc;
        }
    }
}

__device__ __forceinline__ void xg1_body(const f16* __restrict__ h1,
        const uint32_t* __restrict__ wih1T, const float* __restrict__ bih1,
        float* __restrict__ xg, int C, int lgC, int blk, char* smem) {
    u32x4 (*hs)[32] = (u32x4(*)[32])smem;   // 32 KB
    int tid = threadIdx.x;
    int m0 = (blk & (C - 1)) * 64;
    int gbase = (blk >> lgC) * 256;
    const u32x4* hsrc = (const u32x4*)h1 + (size_t)m0 * 32;
    #pragma unroll
    for (int it = 0; it < 4; ++it) {
        int o = tid + it * 512;
        hs[o >> 5][o & 31] = hsrc[o];
    }
    __syncthreads();
    int gg = tid & 31, mg = tid >> 5;
    const u32x4* wt = (const u32x4*)wih1T;
    float acc[8][4];
    #pragma unroll
    for (int i = 0; i < 8; ++i)
        #pragma unroll
        for (int r = 0; r < 4; ++r) acc[i][r] = 0.0f;
    for (int k8 = 0; k8 < 32; ++k8) {
        u32x4 w[8], h[4];
        #pragma unroll
        for (int i = 0; i < 8; ++i) w[i] = wt[(size_t)k8 * 768 + gbase + gg + 32 * i];
        #pragma unroll
        for (int r = 0; r < 4; ++r) h[r] = hs[mg * 4 + r][k8];
        #pragma unroll
        for (int i = 0; i < 8; ++i)
            #pragma unroll
            for (int r = 0; r < 4; ++r)
                acc[i][r] = dot_u4(w[i], h[r], acc[i][r]);
    }
    #pragma unroll
    for (int i = 0; i < 8; ++i) {
        int g = gbase + gg + 32 * i;
        float bias = bih1[g];
        #pragma unroll
        for (int r = 0; r < 4; ++r)
            xg[(size_t)(m0 + mg * 4 + r) * G_ + g] = acc[i][r] + bias;
    }
}

__device__ __forceinline__ void reg_body(const f16* __restrict__ h2,
        const uint32_t* __restrict__ w1T, const float* __restrict__ b1,
        const float* __restrict__ w2, const float* __restrict__ b2,
        float* __restrict__ out, int t0, int C, int lgC, int blk, char* smem) {
    u32x4 (*hs)[32] = (u32x4(*)[32])smem;            // 32 KB
    float (*red)[4] = (float(*)[4])(smem + 32768);   // [16][4]
    int tid = threadIdx.x;
    int m0 = blk * 64;
    const u32x4* hsrc = (const u32x4*)h2 + (size_t)m0 * 32;
    #pragma unroll
    for (int it = 0; it < 4; ++it) {
        int o = tid + it * 512;
        hs[o >> 5][o & 31] = hsrc[o];
    }
    __syncthreads();
    int gg = tid & 31, mg = tid >> 5;
    const u32x4* wt = (const u32x4*)w1T;
    float acc[8][4];
    #pragma unroll
    for (int i = 0; i < 8; ++i)
        #pragma unroll
        for (int r = 0; r < 4; ++r) acc[i][r] = 0.0f;
    for (int k8 = 0; k8 < 32; ++k8) {
        u32x4 w[8], h[4];
        #pragma unroll
        for (int i = 0; i < 8; ++i) w[i] = wt[(size_t)k8 * 256 + gg + 32 * i];
        #pragma unroll
        for (int r = 0; r < 4; ++r) h[r] = hs[mg * 4 + r][k8];
        #pragma unroll
        for (int i = 0; i < 8; ++i)
            #pragma unroll
            for (int r = 0; r < 4; ++r)
                acc[i][r] = dot_u4(w[i], h[r], acc[i][r]);
    }
    float pv[4] = {0, 0, 0, 0};
    #pragma unroll
    for (int i = 0; i < 8; ++i) {
        int g = gg + 32 * i;
        float bias = b1[g], w2g = w2[g];
        #pragma unroll
        for (int r = 0; r < 4; ++r)
            pv[r] += w2g * fmaxf(acc[i][r] + bias, 0.0f);
    }
    #pragma unroll
    for (int r = 0; r < 4; ++r) {
        pv[r] += __shfl_xor(pv[r], 1, 64);
        pv[r] += __shfl_xor(pv[r], 2, 64);
        pv[r] += __shfl_xor(pv[r], 4, 64);
        pv[r] += __shfl_xor(pv[r], 8, 64);
        pv[r] += __shfl_xor(pv[r], 16, 64);
    }
    if (gg == 0) {
        #pragma unroll
        for (int r = 0; r < 4; ++r) red[mg][r] = pv[r];
    }
    __syncthreads();
    if (tid < 64) {
        int m = m0 + tid;
        float v = fmaxf(red[tid >> 2][tid & 3] + b2[0], 0.0f);
        int b = m >> lgC, tl = m & (C - 1);
        out[(size_t)b * T_ + t0 + tl] = v;
    }
}

// ---------- GRU recurrence: TWO batches per WG ----------
// tid = 2j+hf. Weight slice per thread (batch-invariant, paid once):
//   z u0..7 VGPR | n u0..15 + z u8..9 LDS (18 slabs) | z u10..15 + r-fp8 streamed.
// Gate-major order: N+Z pass first (LDS/VGPR; streamed z consumed mid-pass),
// R pass last (fp8 stream consumed ~850cy after issue -> latency hidden).
__device__ __forceinline__ void rec_body(const uint32_t* __restrict__ whh,
        const float* __restrict__ bhh, const float* __restrict__ xg,
        f16* __restrict__ hout, float* __restrict__ state,
        int b0, int C, char* smem) {
    int tid = threadIdx.x;
    int j = tid >> 1, hf = tid & 1;
    const u32x4* wb = (const u32x4*)whh;              // fp16 planes
    const u32x2* w8 = (const u32x2*)(whh + 65536);    // fp8 r planes
    u32x4* wlds = (u32x4*)smem;                       // 18 slabs x [512]
    u32x4 (*hq)[2][2][17] = (u32x4(*)[2][2][17])(smem + 147456); // [bat][p][hf][17]

    // stage slabs thread-major: 0..15 = n (P16..31), 16..17 = z u8,u9
    #pragma unroll
    for (int s = 0; s < 16; ++s)
        wlds[s * 512 + tid] = wb[(16 + s) * 512 + tid];
    wlds[16 * 512 + tid] = wb[8 * 512 + tid];
    wlds[17 * 512 + tid] = wb[9 * 512 + tid];

    // resident z u0..7
    u32x4 Z0 = wb[0 * 512 + tid], Z1 = wb[1 * 512 + tid];
    u32x4 Z2 = wb[2 * 512 + tid], Z3 = wb[3 * 512 + tid];
    u32x4 Z4 = wb[4 * 512 + tid], Z5 = wb[5 * 512 + tid];
    u32x4 Z6 = wb[6 * 512 + tid], Z7 = wb[7 * 512 + tid];

    float h0 = 0.0f, h1 = 0.0f, bhr = 0.0f, bhz = 0.0f, bhn = 0.0f;
    if (hf == 0) {
        h0 = state[b0 * 256 + j];
        h1 = state[(b0 + 1) * 256 + j];
        bhr = bhh[j]; bhz = bhh[256 + j]; bhn = bhh[512 + j];
        ((f16*)&hq[0][0][j >> 7][0])[j & 127] = (f16)h0;
        ((f16*)&hq[1][0][j >> 7][0])[j & 127] = (f16)h1;
    }
    __syncthreads();

    const float* xgt0 = xg + (size_t)b0 * C * G_;
    const float* xgt1 = xgt0 + (size_t)C * G_;
    f16* hob0 = hout + (size_t)b0 * C * H_;
    f16* hob1 = hob0 + (size_t)C * H_;
    const u32x4* nl = wlds + tid;

    for (int tl = 0; tl < C; ++tl) {
        int p = tl & 1;
        // issue streamed loads up-front; consumed late (z mid-NZ, fp8 in R pass)
        u32x4 S10 = wb[10 * 512 + tid], S11 = wb[11 * 512 + tid];
        u32x4 S12 = wb[12 * 512 + tid], S13 = wb[13 * 512 + tid];
        u32x4 S14 = wb[14 * 512 + tid], S15 = wb[15 * 512 + tid];
        u32x2 F0  = w8[ 0 * 512 + tid], F1  = w8[ 1 * 512 + tid];
        u32x2 F2  = w8[ 2 * 512 + tid], F3  = w8[ 3 * 512 + tid];
        u32x2 F4  = w8[ 4 * 512 + tid], F5  = w8[ 5 * 512 + tid];
        u32x2 F6  = w8[ 6 * 512 + tid], F7  = w8[ 7 * 512 + tid];
        u32x2 F8  = w8[ 8 * 512 + tid], F9  = w8[ 9 * 512 + tid];
        u32x2 F10 = w8[10 * 512 + tid], F11 = w8[11 * 512 + tid];
        u32x2 F12 = w8[12 * 512 + tid], F13 = w8[13 * 512 + tid];
        u32x2 F14 = w8[14 * 512 + tid], F15 = w8[15 * 512 + tid];
        float xr0 = 0, xz0 = 0, xn0 = 0, xr1 = 0, xz1 = 0, xn1 = 0;
        if (hf == 0) {
            xr0 = xgt0[j]; xz0 = xgt0[256 + j]; xn0 = xgt0[512 + j];
            xr1 = xgt1[j]; xz1 = xgt1[256 + j]; xn1 = xgt1[512 + j];
        }

        const u32x4* hp0 = &hq[0][p][hf][0];
        const u32x4* hp1 = &hq[1][p][hf][0];
        float aR0 = 0, aZ0 = 0, aN0 = 0, aR1 = 0, aZ1 = 0, aN1 = 0;

        // ---- N+Z pass (no dependency on fp8 stream) ----
#define NZ(u, ZS) { u32x4 v0 = hp0[u], v1 = hp1[u]; \
        u32x4 wn = nl[(u) * 512]; \
        aN0 = dot_u4(wn, v0, aN0); aN1 = dot_u4(wn, v1, aN1); \
        aZ0 = dot_u4(ZS, v0, aZ0); aZ1 = dot_u4(ZS, v1, aZ1); }
        NZ(0, Z0)  NZ(1, Z1)  NZ(2, Z2)  NZ(3, Z3)
        NZ(4, Z4)  NZ(5, Z5)  NZ(6, Z6)  NZ(7, Z7)
        NZ(8,  nl[16 * 512]) NZ(9,  nl[17 * 512])
        NZ(10, S10) NZ(11, S11) NZ(12, S12) NZ(13, S13)
        NZ(14, S14) NZ(15, S15)
#undef NZ

        // ---- R pass (fp8 stream, decoded once, used for both batches) ----
#define RP(u) { u32x4 v0 = hp0[u], v1 = hp1[u]; \
        u32x4 wr; \
        wr.x = __byte_perm(F##u.x, 0u, 0x1404); \
        wr.y = __byte_perm(F##u.x, 0u, 0x3424); \
        wr.z = __byte_perm(F##u.y, 0u, 0x1404); \
        wr.w = __byte_perm(F##u.y, 0u, 0x3424); \
        aR0 = dot_u4(wr, v0, aR0); aR1 = dot_u4(wr, v1, aR1); }
        RP(0)  RP(1)  RP(2)  RP(3)  RP(4)  RP(5)  RP(6)  RP(7)
        RP(8)  RP(9)  RP(10) RP(11) RP(12) RP(13) RP(14) RP(15)
#undef RP

        // combine the two K-halves (adjacent lanes 2j / 2j+1)
        aR0 += __shfl_xor(aR0, 1, 64); aZ0 += __shfl_xor(aZ0, 1, 64);
        aN0 += __shfl_xor(aN0, 1, 64);
        aR1 += __shfl_xor(aR1, 1, 64); aZ1 += __shfl_xor(aZ1, 1, 64);
        aN1 += __shfl_xor(aN1, 1, 64);

        if (hf == 0) {
            float r0 = sigmoid_f(xr0 + aR0 + bhr);
            float z0 = sigmoid_f(xz0 + aZ0 + bhz);
            float n0 = tanh_f(xn0 + r0 * (aN0 + bhn));
            h0 = z0 * (h0 - n0) + n0;
            float r1 = sigmoid_f(xr1 + aR1 + bhr);
            float z1 = sigmoid_f(xz1 + aZ1 + bhz);
            float n1 = tanh_f(xn1 + r1 * (aN1 + bhn));
            h1 = z1 * (h1 - n1) + n1;
            f16 ha = (f16)h0, hb = (f16)h1;
            hob0[(size_t)tl * H_ + j] = ha;
            hob1[(size_t)tl * H_ + j] = hb;
            ((f16*)&hq[0][p ^ 1][j >> 7][0])[j & 127] = ha;
            ((f16*)&hq[1][p ^ 1][j >> 7][0])[j & 127] = hb;
        }
        __syncthreads();
        xgt0 += G_; xgt1 += G_;
    }
    if (hf == 0) {
        state[b0 * 256 + j] = h0;
        state[(b0 + 1) * 256 + j] = h1;
    }
}

// =======================================================================
// fused dispatch, depth-3 pipeline:
//   [0,32)          rec0(i)   batches 2blk,2blk+1
//   [32,64)         rec1(i-2)
//   [64,64+C)       xg0(i+1)
//   [64+C,64+4C)    xg1(i-1)
//   [64+4C,64+5C)   reg(i-3)
// =======================================================================
__global__ __launch_bounds__(512)
__attribute__((amdgpu_waves_per_eu(2, 2)))
void fused_step(int i, int nC, int C, int lgC,
        const float* __restrict__ x,
        const float* __restrict__ wih0, const float* __restrict__ bih0,
        const uint32_t* __restrict__ whh0, const float* __restrict__ bhh0,
        const uint32_t* __restrict__ whh1, const float* __restrict__ bhh1,
        const uint32_t* __restrict__ wih1T, const float* __restrict__ bih1,
        const uint32_t* __restrict__ w1T, const float* __restrict__ b1,
        const float* __restrict__ w2, const float* __restrict__ b2,
        float* __restrict__ xg0a, float* __restrict__ xg0b,
        float* __restrict__ xg1a, float* __restrict__ xg1b,
        f16* __restrict__ h1a, f16* __restrict__ h1b,
        f16* __restrict__ h2a, f16* __restrict__ h2b,
        float* __restrict__ st0, float* __restrict__ st1,
        float* __restrict__ out) {
    extern __shared__ __align__(16) char smem[];
    int blk = blockIdx.x;
    if (blk < 32) {
        if (i >= nC) return;
        rec_body(whh0, bhh0, (i & 1) ? xg0b : xg0a,
                 (i & 1) ? h1b : h1a, st0, blk * 2, C, smem);
    } else if (blk < 64) {
        int c = i - 2;
        if (c < 0 || c >= nC) return;
        rec_body(whh1, bhh1, (c & 1) ? xg1b : xg1a,
                 (c & 1) ? h2b : h2a, st1, (blk - 32) * 2, C, smem);
    } else if (blk < 64 + C) {
        int c = i + 1;
        if (c >= nC) return;
        xg0_body(x, wih0, bih0, (c & 1) ? xg0b : xg0a, c * C, C, blk - 64, smem);
    } else if (blk < 64 + 4 * C) {
        int c = i - 1;
        if (c < 0 || c >= nC) return;
        xg1_body((c & 1) ? h1b : h1a, wih1T, bih1,
                 (c & 1) ? xg1b : xg1a, C, lgC, blk - 64 - C, smem);
    } else {
        int c = i - 3;
        if (c < 0 || c >= nC) return;
        reg_body((c & 1) ? h2b : h2a, w1T, b1, w2, b2, out, c * C, C, lgC,
                 blk - 64 - 4 * C, smem);
    }
}

// ---------- standalone xg0 (chunk 0 prelaunch) ----------
__global__ __launch_bounds__(512) void xg0_stand(const float* __restrict__ x,
        const float* __restrict__ wih0, const float* __restrict__ bih0,
        float* __restrict__ xg, int t0, int C) {
    __shared__ __align__(16) char smem[4096];
    xg0_body(x, wih0, bih0, xg, t0, C, blockIdx.x, smem);
}

// ---------- host ----------
extern "C" void kernel_launch(void* const* d_in, const int* in_sizes, int n_in,
                              void* d_out, int out_size, void* d_ws, size_t ws_size,
                              hipStream_t stream) {
    const float* x    = (const float*)d_in[0];
    const float* Wih0 = (const float*)d_in[1];
    const float* Whh0 = (const float*)d_in[2];
    const float* bih0 = (const float*)d_in[3];
    const float* bhh0 = (const float*)d_in[4];
    const float* Wih1 = (const float*)d_in[5];
    const float* Whh1 = (const float*)d_in[6];
    const float* bih1 = (const float*)d_in[7];
    const float* bhh1 = (const float*)d_in[8];
    const float* W1   = (const float*)d_in[9];
    const float* b1   = (const float*)d_in[10];
    const float* W2   = (const float*)d_in[11];
    const float* b2   = (const float*)d_in[12];
    float* out = (float*)d_out;

    hipFuncSetAttribute(reinterpret_cast<const void*>(fused_step),
                        hipFuncAttributeMaxDynamicSharedMemorySize, REC_SMEM);

    char* ws = (char*)d_ws;
    uint32_t* wcvt = (uint32_t*)ws;             // 294912 dwords
    const uint32_t* whh0c = wcvt;
    const uint32_t* whh1c = wcvt + 81920;
    const uint32_t* wih1T = wcvt + 163840;
    const uint32_t* w1T   = wcvt + 262144;
    float* state0 = (float*)(ws + 1179648);
    float* state1 = (float*)(ws + 1179648 + 65536);
    size_t fixed = 1179648 + 2 * 65536;

    // per-chunk: xg0 x2 + xg1 x2 (196608C each) + h1 x2 + h2 x2 (32768C each)
    int C = 128;
    while (C > 32 && fixed + (size_t)C * 917504 > ws_size) C >>= 1;
    int lgC = 0; while ((1 << lgC) < C) lgC++;
    int nC = T_ / C;

    char* p = ws + fixed;
    float* xg0_buf[2]; float* xg1_buf[2];
    f16* h1_buf[2]; f16* h2_buf[2];
    xg0_buf[0] = (float*)p;  p += (size_t)C * 196608;
    xg0_buf[1] = (float*)p;  p += (size_t)C * 196608;
    xg1_buf[0] = (float*)p;  p += (size_t)C * 196608;
    xg1_buf[1] = (float*)p;  p += (size_t)C * 196608;
    h1_buf[0] = (f16*)p;     p += (size_t)C * 32768;
    h1_buf[1] = (f16*)p;     p += (size_t)C * 32768;
    h2_buf[0] = (f16*)p;     p += (size_t)C * 32768;
    h2_buf[1] = (f16*)p;

    cvt_weights<<<1152, 256, 0, stream>>>(Whh0, Whh1, Wih1, W1, wcvt);
    hipMemsetAsync(state0, 0, 2 * 65536, stream);
    xg0_stand<<<C, 512, 0, stream>>>(x, Wih0, bih0, xg0_buf[0], 0, C);

    for (int i = 0; i <= nC + 2; ++i) {
        fused_step<<<64 + 5 * C, 512, REC_SMEM, stream>>>(i, nC, C, lgC,
            x, Wih0, bih0, whh0c, bhh0, whh1c, bhh1, wih1T, bih1, w1T, b1, W2, b2,
            xg0_buf[0], xg0_buf[1], xg1_buf[0], xg1_buf[1],
            h1_buf[0], h1_buf[1], h2_buf[0], h2_buf[1],
            state0, state1, out);
    }
}

// Round 15
// 3502.222 us; speedup vs baseline: 2.5049x; 2.5049x over previous
//
#include <hip/hip_runtime.h>
#include <hip/hip_fp16.h>
#include <stdint.h>

#define B_ 64
#define T_ 2048
#define I_ 16
#define H_ 256
#define G_ 768   // 3*H

// dynamic LDS: n fp16 x16 slabs (131072) + r fp8 u8..14 x7 slabs (28672)
//            + hq[2][2][17] u32x4 (1088) = 160832  (<= 160 KiB = 163840)
#define REC_SMEM 160832

typedef _Float16 f16;
typedef _Float16 half2_t __attribute__((ext_vector_type(2)));
typedef uint32_t u32x4 __attribute__((ext_vector_type(4)));
typedef uint32_t u32x2 __attribute__((ext_vector_type(2)));

// ---------- fast math helpers ----------
__device__ __forceinline__ float fast_rcp(float x) {
#if __has_builtin(__builtin_amdgcn_rcpf)
    return __builtin_amdgcn_rcpf(x);
#else
    return 1.0f / x;
#endif
}
__device__ __forceinline__ float sigmoid_f(float x) {
    return fast_rcp(1.0f + __expf(-x));
}
__device__ __forceinline__ float tanh_f(float x) {
    float e = __expf(2.0f * x);
    return 1.0f - 2.0f * fast_rcp(e + 1.0f);
}

__device__ __forceinline__ float fdot2(uint32_t a, uint32_t b, float c) {
#if __has_builtin(__builtin_amdgcn_fdot2)
    return __builtin_amdgcn_fdot2(__builtin_bit_cast(half2_t, a),
                                  __builtin_bit_cast(half2_t, b), c, false);
#else
    half2_t ha = __builtin_bit_cast(half2_t, a), hb = __builtin_bit_cast(half2_t, b);
    return c + (float)ha.x * (float)hb.x + (float)ha.y * (float)hb.y;
#endif
}
__device__ __forceinline__ float dot_u4(u32x4 w, u32x4 h, float acc) {
    acc = fdot2(w.x, h.x, acc);
    acc = fdot2(w.y, h.y, acc);
    acc = fdot2(w.z, h.z, acc);
    acc = fdot2(w.w, h.w, acc);
    return acc;
}

// ---------- weight conversion (R12 layout: PROVEN numerics) ----------
// Per Whh layer (stride 81920 dwords; L0 at 0, L1 at 81920):
//   [0,65536): 32 fp16 planes thread-major. u32x4 idx = P*512 + tid, tid=2j+hf.
//     P<16: z gate (row 256+j), u=P.  P>=16: n gate (row 512+j), u=P-16.
//   [65536,81920): 16 fp8-e5m2 r planes. u32x2 idx = P8*512 + tid (row j).
// [163840,262144) Wih1T k-major fp16 | [262144,294912) W1T k-major fp16
__global__ __launch_bounds__(256) void cvt_weights(const float* __restrict__ whh0,
                                                   const float* __restrict__ whh1,
                                                   const float* __restrict__ wih1,
                                                   const float* __restrict__ w1,
                                                   uint32_t* __restrict__ out) {
    int idx = blockIdx.x * 256 + threadIdx.x;
    if (idx >= 294912) return;
    if (idx < 163840) {
        const float* w = (idx < 81920) ? whh0 : whh1;
        int l = (idx < 81920) ? idx : idx - 81920;
        if (l < 65536) {
            int u4 = l >> 2, d = l & 3;
            int P = u4 >> 9, t = u4 & 511;
            int j = t >> 1, hf = t & 1;
            int row = (P < 16) ? (256 + j) : (512 + j);
            int u = (P < 16) ? P : P - 16;
            const float* s = w + (size_t)row * 256 + hf * 128 + u * 8 + d * 2;
            half2_t h;
            h.x = (f16)s[0];
            h.y = (f16)s[1];
            out[idx] = __builtin_bit_cast(uint32_t, h);
        } else {
            int l2 = l - 65536;
            int P8 = l2 >> 10, wd = l2 & 1023;
            int t = wd >> 1, piece = wd & 1;
            int j = t >> 1, hf = t & 1;
            const float* s = w + (size_t)j * 256 + hf * 128 + P8 * 8 + piece * 4;
            uint32_t dw = 0;
            #pragma unroll
            for (int k = 0; k < 4; ++k) {
                f16 hh = (f16)s[k];
                uint16_t hb = __builtin_bit_cast(uint16_t, hh);
                uint16_t r8 = (uint16_t)((hb + 0x7F + ((hb >> 8) & 1)) >> 8); // RN e5m2
                dw |= (uint32_t)(r8 & 0xFF) << (8 * k);
            }
            out[idx] = dw;
        }
    } else if (idx < 262144) {
        int local = idx - 163840;
        int u4 = local >> 2, d = local & 3;
        int k8 = u4 / 768, g = u4 - k8 * 768;
        const float* s = wih1 + (size_t)g * 256 + k8 * 8 + d * 2;
        half2_t h; h.x = (f16)s[0]; h.y = (f16)s[1];
        out[idx] = __builtin_bit_cast(uint32_t, h);
    } else {
        int local = idx - 262144;
        int u4 = local >> 2, d = local & 3;
        int k8 = u4 >> 8, g = u4 & 255;
        const float* s = w1 + (size_t)g * 256 + k8 * 8 + d * 2;
        half2_t h; h.x = (f16)s[0]; h.y = (f16)s[1];
        out[idx] = __builtin_bit_cast(uint32_t, h);
    }
}

// =======================================================================
// role bodies (512 threads each)
// =======================================================================

__device__ __forceinline__ void xg0_body(const float* __restrict__ x,
        const float* __restrict__ wih0, const float* __restrict__ bih0,
        float* __restrict__ xg, int t0, int C, int blk, char* smem) {
    float (*xs)[16] = (float(*)[16])smem;
    int tid = threadIdx.x;
    int m0 = blk * 64;
    if (tid < 256) {
        int r = tid >> 2, c4 = (tid & 3) * 4;
        int m = m0 + r;
        int b = m / C, tl = m - b * C;
        float4 v = *(const float4*)(x + (size_t)(b * T_ + t0 + tl) * I_ + c4);
        *(float4*)&xs[r][c4] = v;
    }
    __syncthreads();
    for (int g = tid; g < G_; g += 512) {
        const float4* wr = (const float4*)(wih0 + (size_t)g * I_);
        float4 w0 = wr[0], w1 = wr[1], w2 = wr[2], w3 = wr[3];
        float bias = bih0[g];
        float* outp = xg + (size_t)m0 * G_ + g;
        for (int m = 0; m < 64; ++m) {
            const float4* xr4 = (const float4*)xs[m];
            float4 a0 = xr4[0], a1 = xr4[1], a2 = xr4[2], a3 = xr4[3];
            float acc = bias;
            acc += a0.x*w0.x + a0.y*w0.y + a0.z*w0.z + a0.w*w0.w;
            acc += a1.x*w1.x + a1.y*w1.y + a1.z*w1.z + a1.w*w1.w;
            acc += a2.x*w2.x + a2.y*w2.y + a2.z*w2.z + a2.w*w2.w;
            acc += a3.x*w3.x + a3.y*w3.y + a3.z*w3.z + a3.w*w3.w;
            outp[(size_t)m * G_] = acc;
        }
    }
}

__device__ __forceinline__ void xg1_body(const f16* __restrict__ h1,
        const uint32_t* __restrict__ wih1T, const float* __restrict__ bih1,
        float* __restrict__ xg, int C, int lgC, int blk, char* smem) {
    u32x4 (*hs)[32] = (u32x4(*)[32])smem;   // 32 KB
    int tid = threadIdx.x;
    int m0 = (blk & (C - 1)) * 64;
    int gbase = (blk >> lgC) * 256;
    const u32x4* hsrc = (const u32x4*)h1 + (size_t)m0 * 32;
    #pragma unroll
    for (int it = 0; it < 4; ++it) {
        int o = tid + it * 512;
        hs[o >> 5][o & 31] = hsrc[o];
    }
    __syncthreads();
    int gg = tid & 31, mg = tid >> 5;
    const u32x4* wt = (const u32x4*)wih1T;
    float acc[8][4];
    #pragma unroll
    for (int i = 0; i < 8; ++i)
        #pragma unroll
        for (int r = 0; r < 4; ++r) acc[i][r] = 0.0f;
    for (int k8 = 0; k8 < 32; ++k8) {
        u32x4 w[8], h[4];
        #pragma unroll
        for (int i = 0; i < 8; ++i) w[i] = wt[(size_t)k8 * 768 + gbase + gg + 32 * i];
        #pragma unroll
        for (int r = 0; r < 4; ++r) h[r] = hs[mg * 4 + r][k8];
        #pragma unroll
        for (int i = 0; i < 8; ++i)
            #pragma unroll
            for (int r = 0; r < 4; ++r)
                acc[i][r] = dot_u4(w[i], h[r], acc[i][r]);
    }
    #pragma unroll
    for (int i = 0; i < 8; ++i) {
        int g = gbase + gg + 32 * i;
        float bias = bih1[g];
        #pragma unroll
        for (int r = 0; r < 4; ++r)
            xg[(size_t)(m0 + mg * 4 + r) * G_ + g] = acc[i][r] + bias;
    }
}

__device__ __forceinline__ void reg_body(const f16* __restrict__ h2,
        const uint32_t* __restrict__ w1T, const float* __restrict__ b1,
        const float* __restrict__ w2, const float* __restrict__ b2,
        float* __restrict__ out, int t0, int C, int lgC, int blk, char* smem) {
    u32x4 (*hs)[32] = (u32x4(*)[32])smem;            // 32 KB
    float (*red)[4] = (float(*)[4])(smem + 32768);   // [16][4]
    int tid = threadIdx.x;
    int m0 = blk * 64;
    const u32x4* hsrc = (const u32x4*)h2 + (size_t)m0 * 32;
    #pragma unroll
    for (int it = 0; it < 4; ++it) {
        int o = tid + it * 512;
        hs[o >> 5][o & 31] = hsrc[o];
    }
    __syncthreads();
    int gg = tid & 31, mg = tid >> 5;
    const u32x4* wt = (const u32x4*)w1T;
    float acc[8][4];
    #pragma unroll
    for (int i = 0; i < 8; ++i)
        #pragma unroll
        for (int r = 0; r < 4; ++r) acc[i][r] = 0.0f;
    for (int k8 = 0; k8 < 32; ++k8) {
        u32x4 w[8], h[4];
        #pragma unroll
        for (int i = 0; i < 8; ++i) w[i] = wt[(size_t)k8 * 256 + gg + 32 * i];
        #pragma unroll
        for (int r = 0; r < 4; ++r) h[r] = hs[mg * 4 + r][k8];
        #pragma unroll
        for (int i = 0; i < 8; ++i)
            #pragma unroll
            for (int r = 0; r < 4; ++r)
                acc[i][r] = dot_u4(w[i], h[r], acc[i][r]);
    }
    float pv[4] = {0, 0, 0, 0};
    #pragma unroll
    for (int i = 0; i < 8; ++i) {
        int g = gg + 32 * i;
        float bias = b1[g], w2g = w2[g];
        #pragma unroll
        for (int r = 0; r < 4; ++r)
            pv[r] += w2g * fmaxf(acc[i][r] + bias, 0.0f);
    }
    #pragma unroll
    for (int r = 0; r < 4; ++r) {
        pv[r] += __shfl_xor(pv[r], 1, 64);
        pv[r] += __shfl_xor(pv[r], 2, 64);
        pv[r] += __shfl_xor(pv[r], 4, 64);
        pv[r] += __shfl_xor(pv[r], 8, 64);
        pv[r] += __shfl_xor(pv[r], 16, 64);
    }
    if (gg == 0) {
        #pragma unroll
        for (int r = 0; r < 4; ++r) red[mg][r] = pv[r];
    }
    __syncthreads();
    if (tid < 64) {
        int m = m0 + tid;
        float v = fmaxf(red[tid >> 2][tid & 3] + b2[0], 0.0f);
        int b = m >> lgC, tl = m & (C - 1);
        out[(size_t)b * T_ + t0 + tl] = v;
    }
}

// ---------- GRU recurrence: minimal-stream split (R12 numerics) ----------
// tid = 2j+hf. Storage (48 plane-slots):
//   VGPR: z u0..7 fp16 (8 quads) + r u0..7 fp8 (8 pairs) = 48 regs (proven cap)
//   LDS:  n u0..15 fp16 (128 KB) + r u8..14 fp8 (28 KB)
//   streamed: z u8..15 fp16 + r u15 fp8 = 68 KB/step (structural floor ~63 KB)
// Streamed loads issued at step head, consumed in the back half of the dots.
__device__ __forceinline__ void rec_body(const uint32_t* __restrict__ whh,
        const float* __restrict__ bhh, const float* __restrict__ xg,
        f16* __restrict__ hout, float* __restrict__ state,
        int b, int C, char* smem) {
    int tid = threadIdx.x;
    int j = tid >> 1, hf = tid & 1;
    const u32x4* wb = (const u32x4*)whh;              // fp16: P0..15 z, P16..31 n
    const u32x2* w8 = (const u32x2*)(whh + 65536);    // fp8 r planes
    u32x4* nl_ = (u32x4*)smem;                        // 16 n slabs
    u32x2* rl_ = (u32x2*)(smem + 131072);             // 7 r slabs (u8..14)
    u32x4 (*hq)[2][17] = (u32x4(*)[2][17])(smem + 159744);

    // stage slabs thread-major (conflict-free)
    #pragma unroll
    for (int s = 0; s < 16; ++s) nl_[s * 512 + tid] = wb[(16 + s) * 512 + tid];
    #pragma unroll
    for (int s = 0; s < 7; ++s)  rl_[s * 512 + tid] = w8[(8 + s) * 512 + tid];

    // VGPR-resident planes (48 regs total — proven allocator grant)
    u32x4 Z0 = wb[0 * 512 + tid], Z1 = wb[1 * 512 + tid];
    u32x4 Z2 = wb[2 * 512 + tid], Z3 = wb[3 * 512 + tid];
    u32x4 Z4 = wb[4 * 512 + tid], Z5 = wb[5 * 512 + tid];
    u32x4 Z6 = wb[6 * 512 + tid], Z7 = wb[7 * 512 + tid];
    u32x2 RF0 = w8[0 * 512 + tid], RF1 = w8[1 * 512 + tid];
    u32x2 RF2 = w8[2 * 512 + tid], RF3 = w8[3 * 512 + tid];
    u32x2 RF4 = w8[4 * 512 + tid], RF5 = w8[5 * 512 + tid];
    u32x2 RF6 = w8[6 * 512 + tid], RF7 = w8[7 * 512 + tid];

    float h_old = 0.0f, bhr = 0.0f, bhz = 0.0f, bhn = 0.0f;
    if (hf == 0) {
        h_old = state[b * 256 + j];
        bhr = bhh[j]; bhz = bhh[256 + j]; bhn = bhh[512 + j];
        ((f16*)&hq[0][j >> 7][0])[j & 127] = (f16)h_old;
    }
    __syncthreads();

    const float* xgt = xg + (size_t)b * C * G_;
    f16* hob = hout + (size_t)b * C * H_;
    const u32x4* nlt = nl_ + tid;
    const u32x2* rlt = rl_ + tid;

    for (int tl = 0; tl < C; ++tl) {
        int p = tl & 1;
        // streamed loads up-front (consumed in the second half of the dots)
        u32x4 S8  = wb[ 8 * 512 + tid], S9  = wb[ 9 * 512 + tid];
        u32x4 S10 = wb[10 * 512 + tid], S11 = wb[11 * 512 + tid];
        u32x4 S12 = wb[12 * 512 + tid], S13 = wb[13 * 512 + tid];
        u32x4 S14 = wb[14 * 512 + tid], S15 = wb[15 * 512 + tid];
        u32x2 FR15 = w8[15 * 512 + tid];
        float xr = 0, xz = 0, xn = 0;
        if (hf == 0) { xr = xgt[j]; xz = xgt[256 + j]; xn = xgt[512 + j]; }

        const u32x4* hp = &hq[p][hf][0];
        float aR = 0.0f, aZ = 0.0f, aN = 0.0f;

#define DEC(Fv, wr) u32x4 wr; \
        wr.x = __byte_perm(Fv.x, 0u, 0x1404); \
        wr.y = __byte_perm(Fv.x, 0u, 0x3424); \
        wr.z = __byte_perm(Fv.y, 0u, 0x1404); \
        wr.w = __byte_perm(Fv.y, 0u, 0x3424);

        // u0..7: fully resident (z VGPR, n LDS, r VGPR-fp8)
#define PUA(u, ZS, RFV) { u32x4 hv = hp[u]; \
        aZ = dot_u4(ZS, hv, aZ); \
        aN = dot_u4(nlt[(u) * 512], hv, aN); \
        { DEC(RFV, wr) aR = dot_u4(wr, hv, aR); } }
        PUA(0, Z0, RF0)  PUA(1, Z1, RF1)  PUA(2, Z2, RF2)  PUA(3, Z3, RF3)
        PUA(4, Z4, RF4)  PUA(5, Z5, RF5)  PUA(6, Z6, RF6)  PUA(7, Z7, RF7)
#undef PUA

        // u8..14: z streamed, n LDS, r LDS-fp8
#define PUB(u, ZS) { u32x4 hv = hp[u]; \
        aZ = dot_u4(ZS, hv, aZ); \
        aN = dot_u4(nlt[(u) * 512], hv, aN); \
        { u32x2 rf = rlt[((u) - 8) * 512]; DEC(rf, wr) aR = dot_u4(wr, hv, aR); } }
        PUB(8,  S8)  PUB(9,  S9)  PUB(10, S10) PUB(11, S11)
        PUB(12, S12) PUB(13, S13) PUB(14, S14)
#undef PUB

        // u15: z streamed, n LDS, r streamed-fp8
        { u32x4 hv = hp[15];
          aZ = dot_u4(S15, hv, aZ);
          aN = dot_u4(nlt[15 * 512], hv, aN);
          { DEC(FR15, wr) aR = dot_u4(wr, hv, aR); } }
#undef DEC

        // combine the two K-halves (adjacent lanes 2j / 2j+1)
        aR += __shfl_xor(aR, 1, 64);
        aZ += __shfl_xor(aZ, 1, 64);
        aN += __shfl_xor(aN, 1, 64);

        if (hf == 0) {
            float r = sigmoid_f(xr + aR + bhr);
            float z = sigmoid_f(xz + aZ + bhz);
            float n = tanh_f(xn + r * (aN + bhn));
            h_old = z * (h_old - n) + n;   // (1-z)*n + z*h
            f16 hh = (f16)h_old;
            hob[(size_t)tl * H_ + j] = hh;
            ((f16*)&hq[p ^ 1][j >> 7][0])[j & 127] = hh;
        }
        __syncthreads();
        xgt += G_;
    }
    if (hf == 0) state[b * 256 + j] = h_old;
}

// =======================================================================
// fused dispatch, depth-3 pipeline:
//   [0,64)          rec0(i)
//   [64,128)        rec1(i-2)
//   [128,128+C)     xg0(i+1)
//   [128+C,128+4C)  xg1(i-1)
//   [128+4C,128+5C) reg(i-3)
// =======================================================================
__global__ __launch_bounds__(512)
__attribute__((amdgpu_waves_per_eu(2, 2)))
void fused_step(int i, int nC, int C, int lgC,
        const float* __restrict__ x,
        const float* __restrict__ wih0, const float* __restrict__ bih0,
        const uint32_t* __restrict__ whh0, const float* __restrict__ bhh0,
        const uint32_t* __restrict__ whh1, const float* __restrict__ bhh1,
        const uint32_t* __restrict__ wih1T, const float* __restrict__ bih1,
        const uint32_t* __restrict__ w1T, const float* __restrict__ b1,
        const float* __restrict__ w2, const float* __restrict__ b2,
        float* __restrict__ xg0a, float* __restrict__ xg0b,
        float* __restrict__ xg1a, float* __restrict__ xg1b,
        f16* __restrict__ h1a, f16* __restrict__ h1b,
        f16* __restrict__ h2a, f16* __restrict__ h2b,
        float* __restrict__ st0, float* __restrict__ st1,
        float* __restrict__ out) {
    extern __shared__ __align__(16) char smem[];
    int blk = blockIdx.x;
    if (blk < 64) {
        if (i >= nC) return;
        rec_body(whh0, bhh0, (i & 1) ? xg0b : xg0a,
                 (i & 1) ? h1b : h1a, st0, blk, C, smem);
    } else if (blk < 128) {
        int c = i - 2;
        if (c < 0 || c >= nC) return;
        rec_body(whh1, bhh1, (c & 1) ? xg1b : xg1a,
                 (c & 1) ? h2b : h2a, st1, blk - 64, C, smem);
    } else if (blk < 128 + C) {
        int c = i + 1;
        if (c >= nC) return;
        xg0_body(x, wih0, bih0, (c & 1) ? xg0b : xg0a, c * C, C, blk - 128, smem);
    } else if (blk < 128 + 4 * C) {
        int c = i - 1;
        if (c < 0 || c >= nC) return;
        xg1_body((c & 1) ? h1b : h1a, wih1T, bih1,
                 (c & 1) ? xg1b : xg1a, C, lgC, blk - 128 - C, smem);
    } else {
        int c = i - 3;
        if (c < 0 || c >= nC) return;
        reg_body((c & 1) ? h2b : h2a, w1T, b1, w2, b2, out, c * C, C, lgC,
                 blk - 128 - 4 * C, smem);
    }
}

// ---------- standalone xg0 (chunk 0 prelaunch) ----------
__global__ __launch_bounds__(512) void xg0_stand(const float* __restrict__ x,
        const float* __restrict__ wih0, const float* __restrict__ bih0,
        float* __restrict__ xg, int t0, int C) {
    __shared__ __align__(16) char smem[4096];
    xg0_body(x, wih0, bih0, xg, t0, C, blockIdx.x, smem);
}

// ---------- host ----------
extern "C" void kernel_launch(void* const* d_in, const int* in_sizes, int n_in,
                              void* d_out, int out_size, void* d_ws, size_t ws_size,
                              hipStream_t stream) {
    const float* x    = (const float*)d_in[0];
    const float* Wih0 = (const float*)d_in[1];
    const float* Whh0 = (const float*)d_in[2];
    const float* bih0 = (const float*)d_in[3];
    const float* bhh0 = (const float*)d_in[4];
    const float* Wih1 = (const float*)d_in[5];
    const float* Whh1 = (const float*)d_in[6];
    const float* bih1 = (const float*)d_in[7];
    const float* bhh1 = (const float*)d_in[8];
    const float* W1   = (const float*)d_in[9];
    const float* b1   = (const float*)d_in[10];
    const float* W2   = (const float*)d_in[11];
    const float* b2   = (const float*)d_in[12];
    float* out = (float*)d_out;

    hipFuncSetAttribute(reinterpret_cast<const void*>(fused_step),
                        hipFuncAttributeMaxDynamicSharedMemorySize, REC_SMEM);

    char* ws = (char*)d_ws;
    uint32_t* wcvt = (uint32_t*)ws;             // 294912 dwords
    const uint32_t* whh0c = wcvt;
    const uint32_t* whh1c = wcvt + 81920;
    const uint32_t* wih1T = wcvt + 163840;
    const uint32_t* w1T   = wcvt + 262144;
    float* state0 = (float*)(ws + 1179648);
    float* state1 = (float*)(ws + 1179648 + 65536);
    size_t fixed = 1179648 + 2 * 65536;

    // per-chunk: xg0 x2 + xg1 x2 (196608C each) + h1 x2 + h2 x2 (32768C each)
    int C = 128;
    while (C > 32 && fixed + (size_t)C * 917504 > ws_size) C >>= 1;
    int lgC = 0; while ((1 << lgC) < C) lgC++;
    int nC = T_ / C;

    char* p = ws + fixed;
    float* xg0_buf[2]; float* xg1_buf[2];
    f16* h1_buf[2]; f16* h2_buf[2];
    xg0_buf[0] = (float*)p;  p += (size_t)C * 196608;
    xg0_buf[1] = (float*)p;  p += (size_t)C * 196608;
    xg1_buf[0] = (float*)p;  p += (size_t)C * 196608;
    xg1_buf[1] = (float*)p;  p += (size_t)C * 196608;
    h1_buf[0] = (f16*)p;     p += (size_t)C * 32768;
    h1_buf[1] = (f16*)p;     p += (size_t)C * 32768;
    h2_buf[0] = (f16*)p;     p += (size_t)C * 32768;
    h2_buf[1] = (f16*)p;

    cvt_weights<<<1152, 256, 0, stream>>>(Whh0, Whh1, Wih1, W1, wcvt);
    hipMemsetAsync(state0, 0, 2 * 65536, stream);
    xg0_stand<<<C, 512, 0, stream>>>(x, Wih0, bih0, xg0_buf[0], 0, C);

    for (int i = 0; i <= nC + 2; ++i) {
        fused_step<<<128 + 5 * C, 512, REC_SMEM, stream>>>(i, nC, C, lgC,
            x, Wih0, bih0, whh0c, bhh0, whh1c, bhh1, wih1T, bih1, w1T, b1, W2, b2,
            xg0_buf[0], xg0_buf[1], xg1_buf[0], xg1_buf[1],
            h1_buf[0], h1_buf[1], h2_buf[0], h2_buf[1],
            state0, state1, out);
    }
}

// Round 16
// 2875.198 us; speedup vs baseline: 3.0512x; 1.2181x over previous
//
#include <hip/hip_runtime.h>
#include <hip/hip_fp16.h>
#include <stdint.h>

#define B_ 64
#define T_ 2048
#define I_ 16
#define H_ 256
#define G_ 768   // 3*H

// dynamic LDS: 19 weight slabs thread-major (155648) + hq[2][2][17] u32x4 (1088)
#define REC_SMEM 156736

typedef _Float16 f16;
typedef _Float16 half2_t __attribute__((ext_vector_type(2)));
typedef uint32_t u32x4 __attribute__((ext_vector_type(4)));
typedef uint32_t u32x2 __attribute__((ext_vector_type(2)));

// ---------- fast math helpers ----------
__device__ __forceinline__ float fast_rcp(float x) {
#if __has_builtin(__builtin_amdgcn_rcpf)
    return __builtin_amdgcn_rcpf(x);
#else
    return 1.0f / x;
#endif
}
__device__ __forceinline__ float sigmoid_f(float x) {
    return fast_rcp(1.0f + __expf(-x));
}
__device__ __forceinline__ float tanh_f(float x) {
    float e = __expf(2.0f * x);
    return 1.0f - 2.0f * fast_rcp(e + 1.0f);
}

__device__ __forceinline__ float fdot2(uint32_t a, uint32_t b, float c) {
#if __has_builtin(__builtin_amdgcn_fdot2)
    return __builtin_amdgcn_fdot2(__builtin_bit_cast(half2_t, a),
                                  __builtin_bit_cast(half2_t, b), c, false);
#else
    half2_t ha = __builtin_bit_cast(half2_t, a), hb = __builtin_bit_cast(half2_t, b);
    return c + (float)ha.x * (float)hb.x + (float)ha.y * (float)hb.y;
#endif
}
__device__ __forceinline__ float dot_u4(u32x4 w, u32x4 h, float acc) {
    acc = fdot2(w.x, h.x, acc);
    acc = fdot2(w.y, h.y, acc);
    acc = fdot2(w.z, h.z, acc);
    acc = fdot2(w.w, h.w, acc);
    return acc;
}

// ---------- weight conversion (R12 layout: proven numerics + perf) ----------
// Per Whh layer (stride 81920 dwords; L0 at 0, L1 at 81920):
//   [0,65536): 32 fp16 planes thread-major. u32x4 idx = P*512 + tid, tid=2j+hf.
//     P<16: z gate (row 256+j), u=P.  P>=16: n gate (row 512+j), u=P-16.
//   [65536,81920): 16 fp8-e5m2 r planes. u32x2 idx = P8*512 + tid (row j).
// [163840,262144) Wih1T k-major fp16 | [262144,294912) W1T k-major fp16
__global__ __launch_bounds__(256) void cvt_weights(const float* __restrict__ whh0,
                                                   const float* __restrict__ whh1,
                                                   const float* __restrict__ wih1,
                                                   const float* __restrict__ w1,
                                                   uint32_t* __restrict__ out) {
    int idx = blockIdx.x * 256 + threadIdx.x;
    if (idx >= 294912) return;
    if (idx < 163840) {
        const float* w = (idx < 81920) ? whh0 : whh1;
        int l = (idx < 81920) ? idx : idx - 81920;
        if (l < 65536) {
            int u4 = l >> 2, d = l & 3;
            int P = u4 >> 9, t = u4 & 511;
            int j = t >> 1, hf = t & 1;
            int row = (P < 16) ? (256 + j) : (512 + j);
            int u = (P < 16) ? P : P - 16;
            const float* s = w + (size_t)row * 256 + hf * 128 + u * 8 + d * 2;
            half2_t h;
            h.x = (f16)s[0];
            h.y = (f16)s[1];
            out[idx] = __builtin_bit_cast(uint32_t, h);
        } else {
            int l2 = l - 65536;
            int P8 = l2 >> 10, wd = l2 & 1023;
            int t = wd >> 1, piece = wd & 1;
            int j = t >> 1, hf = t & 1;
            const float* s = w + (size_t)j * 256 + hf * 128 + P8 * 8 + piece * 4;
            uint32_t dw = 0;
            #pragma unroll
            for (int k = 0; k < 4; ++k) {
                f16 hh = (f16)s[k];
                uint16_t hb = __builtin_bit_cast(uint16_t, hh);
                uint16_t r8 = (uint16_t)((hb + 0x7F + ((hb >> 8) & 1)) >> 8); // RN e5m2
                dw |= (uint32_t)(r8 & 0xFF) << (8 * k);
            }
            out[idx] = dw;
        }
    } else if (idx < 262144) {
        int local = idx - 163840;
        int u4 = local >> 2, d = local & 3;
        int k8 = u4 / 768, g = u4 - k8 * 768;
        const float* s = wih1 + (size_t)g * 256 + k8 * 8 + d * 2;
        half2_t h; h.x = (f16)s[0]; h.y = (f16)s[1];
        out[idx] = __builtin_bit_cast(uint32_t, h);
    } else {
        int local = idx - 262144;
        int u4 = local >> 2, d = local & 3;
        int k8 = u4 >> 8, g = u4 & 255;
        const float* s = w1 + (size_t)g * 256 + k8 * 8 + d * 2;
        half2_t h; h.x = (f16)s[0]; h.y = (f16)s[1];
        out[idx] = __builtin_bit_cast(uint32_t, h);
    }
}

// =======================================================================
// role bodies (512 threads each)
// =======================================================================

__device__ __forceinline__ void xg0_body(const float* __restrict__ x,
        const float* __restrict__ wih0, const float* __restrict__ bih0,
        float* __restrict__ xg, int t0, int C, int blk, char* smem) {
    float (*xs)[16] = (float(*)[16])smem;
    int tid = threadIdx.x;
    int m0 = blk * 64;
    if (tid < 256) {
        int r = tid >> 2, c4 = (tid & 3) * 4;
        int m = m0 + r;
        int b = m / C, tl = m - b * C;
        float4 v = *(const float4*)(x + (size_t)(b * T_ + t0 + tl) * I_ + c4);
        *(float4*)&xs[r][c4] = v;
    }
    __syncthreads();
    for (int g = tid; g < G_; g += 512) {
        const float4* wr = (const float4*)(wih0 + (size_t)g * I_);
        float4 w0 = wr[0], w1 = wr[1], w2 = wr[2], w3 = wr[3];
        float bias = bih0[g];
        float* outp = xg + (size_t)m0 * G_ + g;
        for (int m = 0; m < 64; ++m) {
            const float4* xr4 = (const float4*)xs[m];
            float4 a0 = xr4[0], a1 = xr4[1], a2 = xr4[2], a3 = xr4[3];
            float acc = bias;
            acc += a0.x*w0.x + a0.y*w0.y + a0.z*w0.z + a0.w*w0.w;
            acc += a1.x*w1.x + a1.y*w1.y + a1.z*w1.z + a1.w*w1.w;
            acc += a2.x*w2.x + a2.y*w2.y + a2.z*w2.z + a2.w*w2.w;
            acc += a3.x*w3.x + a3.y*w3.y + a3.z*w3.z + a3.w*w3.w;
            outp[(size_t)m * G_] = acc;
        }
    }
}

__device__ __forceinline__ void xg1_body(const f16* __restrict__ h1,
        const uint32_t* __restrict__ wih1T, const float* __restrict__ bih1,
        float* __restrict__ xg, int C, int lgC, int blk, char* smem) {
    u32x4 (*hs)[32] = (u32x4(*)[32])smem;   // 32 KB
    int tid = threadIdx.x;
    int m0 = (blk & (C - 1)) * 64;
    int gbase = (blk >> lgC) * 256;
    const u32x4* hsrc = (const u32x4*)h1 + (size_t)m0 * 32;
    #pragma unroll
    for (int it = 0; it < 4; ++it) {
        int o = tid + it * 512;
        hs[o >> 5][o & 31] = hsrc[o];
    }
    __syncthreads();
    int gg = tid & 31, mg = tid >> 5;
    const u32x4* wt = (const u32x4*)wih1T;
    float acc[8][4];
    #pragma unroll
    for (int i = 0; i < 8; ++i)
        #pragma unroll
        for (int r = 0; r < 4; ++r) acc[i][r] = 0.0f;
    for (int k8 = 0; k8 < 32; ++k8) {
        u32x4 w[8], h[4];
        #pragma unroll
        for (int i = 0; i < 8; ++i) w[i] = wt[(size_t)k8 * 768 + gbase + gg + 32 * i];
        #pragma unroll
        for (int r = 0; r < 4; ++r) h[r] = hs[mg * 4 + r][k8];
        #pragma unroll
        for (int i = 0; i < 8; ++i)
            #pragma unroll
            for (int r = 0; r < 4; ++r)
                acc[i][r] = dot_u4(w[i], h[r], acc[i][r]);
    }
    #pragma unroll
    for (int i = 0; i < 8; ++i) {
        int g = gbase + gg + 32 * i;
        float bias = bih1[g];
        #pragma unroll
        for (int r = 0; r < 4; ++r)
            xg[(size_t)(m0 + mg * 4 + r) * G_ + g] = acc[i][r] + bias;
    }
}

__device__ __forceinline__ void reg_body(const f16* __restrict__ h2,
        const uint32_t* __restrict__ w1T, const float* __restrict__ b1,
        const float* __restrict__ w2, const float* __restrict__ b2,
        float* __restrict__ out, int t0, int C, int lgC, int blk, char* smem) {
    u32x4 (*hs)[32] = (u32x4(*)[32])smem;            // 32 KB
    float (*red)[4] = (float(*)[4])(smem + 32768);   // [16][4]
    int tid = threadIdx.x;
    int m0 = blk * 64;
    const u32x4* hsrc = (const u32x4*)h2 + (size_t)m0 * 32;
    #pragma unroll
    for (int it = 0; it < 4; ++it) {
        int o = tid + it * 512;
        hs[o >> 5][o & 31] = hsrc[o];
    }
    __syncthreads();
    int gg = tid & 31, mg = tid >> 5;
    const u32x4* wt = (const u32x4*)w1T;
    float acc[8][4];
    #pragma unroll
    for (int i = 0; i < 8; ++i)
        #pragma unroll
        for (int r = 0; r < 4; ++r) acc[i][r] = 0.0f;
    for (int k8 = 0; k8 < 32; ++k8) {
        u32x4 w[8], h[4];
        #pragma unroll
        for (int i = 0; i < 8; ++i) w[i] = wt[(size_t)k8 * 256 + gg + 32 * i];
        #pragma unroll
        for (int r = 0; r < 4; ++r) h[r] = hs[mg * 4 + r][k8];
        #pragma unroll
        for (int i = 0; i < 8; ++i)
            #pragma unroll
            for (int r = 0; r < 4; ++r)
                acc[i][r] = dot_u4(w[i], h[r], acc[i][r]);
    }
    float pv[4] = {0, 0, 0, 0};
    #pragma unroll
    for (int i = 0; i < 8; ++i) {
        int g = gg + 32 * i;
        float bias = b1[g], w2g = w2[g];
        #pragma unroll
        for (int r = 0; r < 4; ++r)
            pv[r] += w2g * fmaxf(acc[i][r] + bias, 0.0f);
    }
    #pragma unroll
    for (int r = 0; r < 4; ++r) {
        pv[r] += __shfl_xor(pv[r], 1, 64);
        pv[r] += __shfl_xor(pv[r], 2, 64);
        pv[r] += __shfl_xor(pv[r], 4, 64);
        pv[r] += __shfl_xor(pv[r], 8, 64);
        pv[r] += __shfl_xor(pv[r], 16, 64);
    }
    if (gg == 0) {
        #pragma unroll
        for (int r = 0; r < 4; ++r) red[mg][r] = pv[r];
    }
    __syncthreads();
    if (tid < 64) {
        int m = m0 + tid;
        float v = fmaxf(red[tid >> 2][tid & 3] + b2[0], 0.0f);
        int b = m >> lgC, tl = m & (C - 1);
        out[(size_t)b * T_ + t0 + tl] = v;
    }
}

// ---------- GRU recurrence (R12 split + LDS software-pipelining) ----------
// tid = 2j+hf. Split: z u0..11 VGPR fp16 | n u0..15 + z u12..14 LDS (19 slabs)
// | r u0..15 fp8 + z u15 streamed. NEW: n-plane LDS reads run through a
// 6-deep rotating register window (issue at PU(u-6), consume at PU(u)) and
// the 3 z-LDS reads are hoisted to the step head — every ds_read now has
// ~6 PU iterations of independent work between issue and use.
__device__ __forceinline__ void rec_body(const uint32_t* __restrict__ whh,
        const float* __restrict__ bhh, const float* __restrict__ xg,
        f16* __restrict__ hout, float* __restrict__ state,
        int b, int C, char* smem) {
    int tid = threadIdx.x;
    int j = tid >> 1, hf = tid & 1;
    const u32x4* wb = (const u32x4*)whh;              // fp16 planes
    const u32x2* w8 = (const u32x2*)(whh + 65536);    // fp8 r planes
    u32x4* wlds = (u32x4*)smem;                       // 19 slabs x [512]
    u32x4 (*hq)[2][17] = (u32x4(*)[2][17])(smem + 155648);

    // stage slabs thread-major: 0..15 = n (P=16..31), 16..18 = z u12..14
    #pragma unroll
    for (int s = 0; s < 16; ++s)
        wlds[s * 512 + tid] = wb[(16 + s) * 512 + tid];
    #pragma unroll
    for (int s = 0; s < 3; ++s)
        wlds[(16 + s) * 512 + tid] = wb[(12 + s) * 512 + tid];

    // resident z u0..11
    u32x4 Z0  = wb[ 0 * 512 + tid], Z1  = wb[ 1 * 512 + tid];
    u32x4 Z2  = wb[ 2 * 512 + tid], Z3  = wb[ 3 * 512 + tid];
    u32x4 Z4  = wb[ 4 * 512 + tid], Z5  = wb[ 5 * 512 + tid];
    u32x4 Z6  = wb[ 6 * 512 + tid], Z7  = wb[ 7 * 512 + tid];
    u32x4 Z8  = wb[ 8 * 512 + tid], Z9  = wb[ 9 * 512 + tid];
    u32x4 Z10 = wb[10 * 512 + tid], Z11 = wb[11 * 512 + tid];

    float h_old = 0.0f, bhr = 0.0f, bhz = 0.0f, bhn = 0.0f;
    if (hf == 0) {
        h_old = state[b * 256 + j];
        bhr = bhh[j]; bhz = bhh[256 + j]; bhn = bhh[512 + j];
        ((f16*)&hq[0][j >> 7][0])[j & 127] = (f16)h_old;
    }
    __syncthreads();

    const float* xgt = xg + (size_t)b * C * G_;
    f16* hob = hout + (size_t)b * C * H_;
    const u32x4* nl = wlds + tid;

    for (int tl = 0; tl < C; ++tl) {
        int p = tl & 1;
        // streamed global loads: all fp8 r planes + z u15 + input gates
        u32x2 F0  = w8[ 0 * 512 + tid], F1  = w8[ 1 * 512 + tid];
        u32x2 F2  = w8[ 2 * 512 + tid], F3  = w8[ 3 * 512 + tid];
        u32x2 F4  = w8[ 4 * 512 + tid], F5  = w8[ 5 * 512 + tid];
        u32x2 F6  = w8[ 6 * 512 + tid], F7  = w8[ 7 * 512 + tid];
        u32x2 F8  = w8[ 8 * 512 + tid], F9  = w8[ 9 * 512 + tid];
        u32x2 F10 = w8[10 * 512 + tid], F11 = w8[11 * 512 + tid];
        u32x2 F12 = w8[12 * 512 + tid], F13 = w8[13 * 512 + tid];
        u32x2 F14 = w8[14 * 512 + tid], F15 = w8[15 * 512 + tid];
        u32x4 SZ = wb[15 * 512 + tid];
        float xr = 0, xz = 0, xn = 0;
        if (hf == 0) { xr = xgt[j]; xz = xgt[256 + j]; xn = xgt[512 + j]; }

        const u32x4* hp = &hq[p][hf][0];

        // LDS prefetch: 6-deep n-window + hoisted z u12..14 reads
        u32x4 N0 = nl[0 * 512], N1 = nl[1 * 512], N2 = nl[2 * 512];
        u32x4 N3 = nl[3 * 512], N4 = nl[4 * 512], N5 = nl[5 * 512];
        u32x4 ZL12 = nl[16 * 512], ZL13 = nl[17 * 512], ZL14 = nl[18 * 512];

        float aR = 0.0f, aZ = 0.0f, aN = 0.0f;

#define PU(u, ZS, NV) { u32x4 hv = hp[u]; \
        aZ = dot_u4(ZS, hv, aZ); \
        aN = dot_u4(NV, hv, aN); \
        u32x4 wr; \
        wr.x = __byte_perm(F##u.x, 0u, 0x1404); \
        wr.y = __byte_perm(F##u.x, 0u, 0x3424); \
        wr.z = __byte_perm(F##u.y, 0u, 0x1404); \
        wr.w = __byte_perm(F##u.y, 0u, 0x3424); \
        aR = dot_u4(wr, hv, aR); }

        PU(0,  Z0,  N0)  N0 = nl[ 6 * 512];
        PU(1,  Z1,  N1)  N1 = nl[ 7 * 512];
        PU(2,  Z2,  N2)  N2 = nl[ 8 * 512];
        PU(3,  Z3,  N3)  N3 = nl[ 9 * 512];
        PU(4,  Z4,  N4)  N4 = nl[10 * 512];
        PU(5,  Z5,  N5)  N5 = nl[11 * 512];
        PU(6,  Z6,  N0)  N0 = nl[12 * 512];
        PU(7,  Z7,  N1)  N1 = nl[13 * 512];
        PU(8,  Z8,  N2)  N2 = nl[14 * 512];
        PU(9,  Z9,  N3)  N3 = nl[15 * 512];
        PU(10, Z10, N4)
        PU(11, Z11, N5)
        PU(12, ZL12, N0)
        PU(13, ZL13, N1)
        PU(14, ZL14, N2)
        PU(15, SZ,   N3)
#undef PU

        // combine the two K-halves (adjacent lanes 2j / 2j+1)
        aR += __shfl_xor(aR, 1, 64);
        aZ += __shfl_xor(aZ, 1, 64);
        aN += __shfl_xor(aN, 1, 64);

        if (hf == 0) {
            float r = sigmoid_f(xr + aR + bhr);
            float z = sigmoid_f(xz + aZ + bhz);
            float n = tanh_f(xn + r * (aN + bhn));
            h_old = z * (h_old - n) + n;   // (1-z)*n + z*h
            f16 hh = (f16)h_old;
            hob[(size_t)tl * H_ + j] = hh;
            ((f16*)&hq[p ^ 1][j >> 7][0])[j & 127] = hh;
        }
        __syncthreads();
        xgt += G_;
    }
    if (hf == 0) state[b * 256 + j] = h_old;
}

// =======================================================================
// fused dispatch, depth-3 pipeline:
//   [0,64)          rec0(i)
//   [64,128)        rec1(i-2)
//   [128,128+C)     xg0(i+1)
//   [128+C,128+4C)  xg1(i-1)
//   [128+4C,128+5C) reg(i-3)
// =======================================================================
__global__ __launch_bounds__(512)
__attribute__((amdgpu_waves_per_eu(2, 2)))
void fused_step(int i, int nC, int C, int lgC,
        const float* __restrict__ x,
        const float* __restrict__ wih0, const float* __restrict__ bih0,
        const uint32_t* __restrict__ whh0, const float* __restrict__ bhh0,
        const uint32_t* __restrict__ whh1, const float* __restrict__ bhh1,
        const uint32_t* __restrict__ wih1T, const float* __restrict__ bih1,
        const uint32_t* __restrict__ w1T, const float* __restrict__ b1,
        const float* __restrict__ w2, const float* __restrict__ b2,
        float* __restrict__ xg0a, float* __restrict__ xg0b,
        float* __restrict__ xg1a, float* __restrict__ xg1b,
        f16* __restrict__ h1a, f16* __restrict__ h1b,
        f16* __restrict__ h2a, f16* __restrict__ h2b,
        float* __restrict__ st0, float* __restrict__ st1,
        float* __restrict__ out) {
    extern __shared__ __align__(16) char smem[];
    int blk = blockIdx.x;
    if (blk < 64) {
        if (i >= nC) return;
        rec_body(whh0, bhh0, (i & 1) ? xg0b : xg0a,
                 (i & 1) ? h1b : h1a, st0, blk, C, smem);
    } else if (blk < 128) {
        int c = i - 2;
        if (c < 0 || c >= nC) return;
        rec_body(whh1, bhh1, (c & 1) ? xg1b : xg1a,
                 (c & 1) ? h2b : h2a, st1, blk - 64, C, smem);
    } else if (blk < 128 + C) {
        int c = i + 1;
        if (c >= nC) return;
        xg0_body(x, wih0, bih0, (c & 1) ? xg0b : xg0a, c * C, C, blk - 128, smem);
    } else if (blk < 128 + 4 * C) {
        int c = i - 1;
        if (c < 0 || c >= nC) return;
        xg1_body((c & 1) ? h1b : h1a, wih1T, bih1,
                 (c & 1) ? xg1b : xg1a, C, lgC, blk - 128 - C, smem);
    } else {
        int c = i - 3;
        if (c < 0 || c >= nC) return;
        reg_body((c & 1) ? h2b : h2a, w1T, b1, w2, b2, out, c * C, C, lgC,
                 blk - 128 - 4 * C, smem);
    }
}

// ---------- standalone xg0 (chunk 0 prelaunch) ----------
__global__ __launch_bounds__(512) void xg0_stand(const float* __restrict__ x,
        const float* __restrict__ wih0, const float* __restrict__ bih0,
        float* __restrict__ xg, int t0, int C) {
    __shared__ __align__(16) char smem[4096];
    xg0_body(x, wih0, bih0, xg, t0, C, blockIdx.x, smem);
}

// ---------- host ----------
extern "C" void kernel_launch(void* const* d_in, const int* in_sizes, int n_in,
                              void* d_out, int out_size, void* d_ws, size_t ws_size,
                              hipStream_t stream) {
    const float* x    = (const float*)d_in[0];
    const float* Wih0 = (const float*)d_in[1];
    const float* Whh0 = (const float*)d_in[2];
    const float* bih0 = (const float*)d_in[3];
    const float* bhh0 = (const float*)d_in[4];
    const float* Wih1 = (const float*)d_in[5];
    const float* Whh1 = (const float*)d_in[6];
    const float* bih1 = (const float*)d_in[7];
    const float* bhh1 = (const float*)d_in[8];
    const float* W1   = (const float*)d_in[9];
    const float* b1   = (const float*)d_in[10];
    const float* W2   = (const float*)d_in[11];
    const float* b2   = (const float*)d_in[12];
    float* out = (float*)d_out;

    hipFuncSetAttribute(reinterpret_cast<const void*>(fused_step),
                        hipFuncAttributeMaxDynamicSharedMemorySize, REC_SMEM);

    char* ws = (char*)d_ws;
    uint32_t* wcvt = (uint32_t*)ws;             // 294912 dwords
    const uint32_t* whh0c = wcvt;
    const uint32_t* whh1c = wcvt + 81920;
    const uint32_t* wih1T = wcvt + 163840;
    const uint32_t* w1T   = wcvt + 262144;
    float* state0 = (float*)(ws + 1179648);
    float* state1 = (float*)(ws + 1179648 + 65536);
    size_t fixed = 1179648 + 2 * 65536;

    // per-chunk: xg0 x2 + xg1 x2 (196608C each) + h1 x2 + h2 x2 (32768C each)
    int C = 128;
    while (C > 32 && fixed + (size_t)C * 917504 > ws_size) C >>= 1;
    int lgC = 0; while ((1 << lgC) < C) lgC++;
    int nC = T_ / C;

    char* p = ws + fixed;
    float* xg0_buf[2]; float* xg1_buf[2];
    f16* h1_buf[2]; f16* h2_buf[2];
    xg0_buf[0] = (float*)p;  p += (size_t)C * 196608;
    xg0_buf[1] = (float*)p;  p += (size_t)C * 196608;
    xg1_buf[0] = (float*)p;  p += (size_t)C * 196608;
    xg1_buf[1] = (float*)p;  p += (size_t)C * 196608;
    h1_buf[0] = (f16*)p;     p += (size_t)C * 32768;
    h1_buf[1] = (f16*)p;     p += (size_t)C * 32768;
    h2_buf[0] = (f16*)p;     p += (size_t)C * 32768;
    h2_buf[1] = (f16*)p;

    cvt_weights<<<1152, 256, 0, stream>>>(Whh0, Whh1, Wih1, W1, wcvt);
    hipMemsetAsync(state0, 0, 2 * 65536, stream);
    xg0_stand<<<C, 512, 0, stream>>>(x, Wih0, bih0, xg0_buf[0], 0, C);

    for (int i = 0; i <= nC + 2; ++i) {
        fused_step<<<128 + 5 * C, 512, REC_SMEM, stream>>>(i, nC, C, lgC,
            x, Wih0, bih0, whh0c, bhh0, whh1c, bhh1, wih1T, bih1, w1T, b1, W2, b2,
            xg0_buf[0], xg0_buf[1], xg1_buf[0], xg1_buf[1],
            h1_buf[0], h1_buf[1], h2_buf[0], h2_buf[1],
            state0, state1, out);
    }
}

// Round 17
// 2742.996 us; speedup vs baseline: 3.1983x; 1.0482x over previous
//
#include <hip/hip_runtime.h>
#include <hip/hip_fp16.h>
#include <stdint.h>

#define B_ 64
#define T_ 2048
#define I_ 16
#define H_ 256
#define G_ 768   // 3*H

// dynamic LDS: 19 weight slabs thread-major (155648) + hq[2][2][17] u32x4 (1088)
#define REC_SMEM 156736

typedef _Float16 f16;
typedef _Float16 half2_t __attribute__((ext_vector_type(2)));
typedef uint32_t u32x4 __attribute__((ext_vector_type(4)));
typedef uint32_t u32x2 __attribute__((ext_vector_type(2)));

// ---------- fast math helpers ----------
__device__ __forceinline__ float fast_rcp(float x) {
#if __has_builtin(__builtin_amdgcn_rcpf)
    return __builtin_amdgcn_rcpf(x);
#else
    return 1.0f / x;
#endif
}
__device__ __forceinline__ float sigmoid_f(float x) {
    return fast_rcp(1.0f + __expf(-x));
}
__device__ __forceinline__ float tanh_f(float x) {
    float e = __expf(2.0f * x);
    return 1.0f - 2.0f * fast_rcp(e + 1.0f);
}

__device__ __forceinline__ float fdot2(uint32_t a, uint32_t b, float c) {
#if __has_builtin(__builtin_amdgcn_fdot2)
    return __builtin_amdgcn_fdot2(__builtin_bit_cast(half2_t, a),
                                  __builtin_bit_cast(half2_t, b), c, false);
#else
    half2_t ha = __builtin_bit_cast(half2_t, a), hb = __builtin_bit_cast(half2_t, b);
    return c + (float)ha.x * (float)hb.x + (float)ha.y * (float)hb.y;
#endif
}
__device__ __forceinline__ float dot_u4(u32x4 w, u32x4 h, float acc) {
    acc = fdot2(w.x, h.x, acc);
    acc = fdot2(w.y, h.y, acc);
    acc = fdot2(w.z, h.z, acc);
    acc = fdot2(w.w, h.w, acc);
    return acc;
}

// ---------- weight conversion (R12 layout: proven numerics + perf) ----------
// Per Whh layer (stride 81920 dwords; L0 at 0, L1 at 81920):
//   [0,65536): 32 fp16 planes thread-major. u32x4 idx = P*512 + tid, tid=2j+hf.
//     P<16: z gate (row 256+j), u=P.  P>=16: n gate (row 512+j), u=P-16.
//   [65536,81920): 16 fp8-e5m2 r planes. u32x2 idx = P8*512 + tid (row j).
// [163840,262144) Wih1T k-major fp16 | [262144,294912) W1T k-major fp16
__global__ __launch_bounds__(256) void cvt_weights(const float* __restrict__ whh0,
                                                   const float* __restrict__ whh1,
                                                   const float* __restrict__ wih1,
                                                   const float* __restrict__ w1,
                                                   uint32_t* __restrict__ out) {
    int idx = blockIdx.x * 256 + threadIdx.x;
    if (idx >= 294912) return;
    if (idx < 163840) {
        const float* w = (idx < 81920) ? whh0 : whh1;
        int l = (idx < 81920) ? idx : idx - 81920;
        if (l < 65536) {
            int u4 = l >> 2, d = l & 3;
            int P = u4 >> 9, t = u4 & 511;
            int j = t >> 1, hf = t & 1;
            int row = (P < 16) ? (256 + j) : (512 + j);
            int u = (P < 16) ? P : P - 16;
            const float* s = w + (size_t)row * 256 + hf * 128 + u * 8 + d * 2;
            half2_t h;
            h.x = (f16)s[0];
            h.y = (f16)s[1];
            out[idx] = __builtin_bit_cast(uint32_t, h);
        } else {
            int l2 = l - 65536;
            int P8 = l2 >> 10, wd = l2 & 1023;
            int t = wd >> 1, piece = wd & 1;
            int j = t >> 1, hf = t & 1;
            const float* s = w + (size_t)j * 256 + hf * 128 + P8 * 8 + piece * 4;
            uint32_t dw = 0;
            #pragma unroll
            for (int k = 0; k < 4; ++k) {
                f16 hh = (f16)s[k];
                uint16_t hb = __builtin_bit_cast(uint16_t, hh);
                uint16_t r8 = (uint16_t)((hb + 0x7F + ((hb >> 8) & 1)) >> 8); // RN e5m2
                dw |= (uint32_t)(r8 & 0xFF) << (8 * k);
            }
            out[idx] = dw;
        }
    } else if (idx < 262144) {
        int local = idx - 163840;
        int u4 = local >> 2, d = local & 3;
        int k8 = u4 / 768, g = u4 - k8 * 768;
        const float* s = wih1 + (size_t)g * 256 + k8 * 8 + d * 2;
        half2_t h; h.x = (f16)s[0]; h.y = (f16)s[1];
        out[idx] = __builtin_bit_cast(uint32_t, h);
    } else {
        int local = idx - 262144;
        int u4 = local >> 2, d = local & 3;
        int k8 = u4 >> 8, g = u4 & 255;
        const float* s = w1 + (size_t)g * 256 + k8 * 8 + d * 2;
        half2_t h; h.x = (f16)s[0]; h.y = (f16)s[1];
        out[idx] = __builtin_bit_cast(uint32_t, h);
    }
}

// =======================================================================
// role bodies (512 threads each)
// =======================================================================

__device__ __forceinline__ void xg0_body(const float* __restrict__ x,
        const float* __restrict__ wih0, const float* __restrict__ bih0,
        float* __restrict__ xg, int t0, int C, int blk, char* smem) {
    float (*xs)[16] = (float(*)[16])smem;
    int tid = threadIdx.x;
    int m0 = blk * 64;
    if (tid < 256) {
        int r = tid >> 2, c4 = (tid & 3) * 4;
        int m = m0 + r;
        int b = m / C, tl = m - b * C;
        float4 v = *(const float4*)(x + (size_t)(b * T_ + t0 + tl) * I_ + c4);
        *(float4*)&xs[r][c4] = v;
    }
    __syncthreads();
    for (int g = tid; g < G_; g += 512) {
        const float4* wr = (const float4*)(wih0 + (size_t)g * I_);
        float4 w0 = wr[0], w1 = wr[1], w2 = wr[2], w3 = wr[3];
        float bias = bih0[g];
        float* outp = xg + (size_t)m0 * G_ + g;
        for (int m = 0; m < 64; ++m) {
            const float4* xr4 = (const float4*)xs[m];
            float4 a0 = xr4[0], a1 = xr4[1], a2 = xr4[2], a3 = xr4[3];
            float acc = bias;
            acc += a0.x*w0.x + a0.y*w0.y + a0.z*w0.z + a0.w*w0.w;
            acc += a1.x*w1.x + a1.y*w1.y + a1.z*w1.z + a1.w*w1.w;
            acc += a2.x*w2.x + a2.y*w2.y + a2.z*w2.z + a2.w*w2.w;
            acc += a3.x*w3.x + a3.y*w3.y + a3.z*w3.z + a3.w*w3.w;
            outp[(size_t)m * G_] = acc;
        }
    }
}

__device__ __forceinline__ void xg1_body(const f16* __restrict__ h1,
        const uint32_t* __restrict__ wih1T, const float* __restrict__ bih1,
        float* __restrict__ xg, int C, int lgC, int blk, char* smem) {
    u32x4 (*hs)[32] = (u32x4(*)[32])smem;   // 32 KB
    int tid = threadIdx.x;
    int m0 = (blk & (C - 1)) * 64;
    int gbase = (blk >> lgC) * 256;
    const u32x4* hsrc = (const u32x4*)h1 + (size_t)m0 * 32;
    #pragma unroll
    for (int it = 0; it < 4; ++it) {
        int o = tid + it * 512;
        hs[o >> 5][o & 31] = hsrc[o];
    }
    __syncthreads();
    int gg = tid & 31, mg = tid >> 5;
    const u32x4* wt = (const u32x4*)wih1T;
    float acc[8][4];
    #pragma unroll
    for (int i = 0; i < 8; ++i)
        #pragma unroll
        for (int r = 0; r < 4; ++r) acc[i][r] = 0.0f;
    for (int k8 = 0; k8 < 32; ++k8) {
        u32x4 w[8], h[4];
        #pragma unroll
        for (int i = 0; i < 8; ++i) w[i] = wt[(size_t)k8 * 768 + gbase + gg + 32 * i];
        #pragma unroll
        for (int r = 0; r < 4; ++r) h[r] = hs[mg * 4 + r][k8];
        #pragma unroll
        for (int i = 0; i < 8; ++i)
            #pragma unroll
            for (int r = 0; r < 4; ++r)
                acc[i][r] = dot_u4(w[i], h[r], acc[i][r]);
    }
    #pragma unroll
    for (int i = 0; i < 8; ++i) {
        int g = gbase + gg + 32 * i;
        float bias = bih1[g];
        #pragma unroll
        for (int r = 0; r < 4; ++r)
            xg[(size_t)(m0 + mg * 4 + r) * G_ + g] = acc[i][r] + bias;
    }
}

__device__ __forceinline__ void reg_body(const f16* __restrict__ h2,
        const uint32_t* __restrict__ w1T, const float* __restrict__ b1,
        const float* __restrict__ w2, const float* __restrict__ b2,
        float* __restrict__ out, int t0, int C, int lgC, int blk, char* smem) {
    u32x4 (*hs)[32] = (u32x4(*)[32])smem;            // 32 KB
    float (*red)[4] = (float(*)[4])(smem + 32768);   // [16][4]
    int tid = threadIdx.x;
    int m0 = blk * 64;
    const u32x4* hsrc = (const u32x4*)h2 + (size_t)m0 * 32;
    #pragma unroll
    for (int it = 0; it < 4; ++it) {
        int o = tid + it * 512;
        hs[o >> 5][o & 31] = hsrc[o];
    }
    __syncthreads();
    int gg = tid & 31, mg = tid >> 5;
    const u32x4* wt = (const u32x4*)w1T;
    float acc[8][4];
    #pragma unroll
    for (int i = 0; i < 8; ++i)
        #pragma unroll
        for (int r = 0; r < 4; ++r) acc[i][r] = 0.0f;
    for (int k8 = 0; k8 < 32; ++k8) {
        u32x4 w[8], h[4];
        #pragma unroll
        for (int i = 0; i < 8; ++i) w[i] = wt[(size_t)k8 * 256 + gg + 32 * i];
        #pragma unroll
        for (int r = 0; r < 4; ++r) h[r] = hs[mg * 4 + r][k8];
        #pragma unroll
        for (int i = 0; i < 8; ++i)
            #pragma unroll
            for (int r = 0; r < 4; ++r)
                acc[i][r] = dot_u4(w[i], h[r], acc[i][r]);
    }
    float pv[4] = {0, 0, 0, 0};
    #pragma unroll
    for (int i = 0; i < 8; ++i) {
        int g = gg + 32 * i;
        float bias = b1[g], w2g = w2[g];
        #pragma unroll
        for (int r = 0; r < 4; ++r)
            pv[r] += w2g * fmaxf(acc[i][r] + bias, 0.0f);
    }
    #pragma unroll
    for (int r = 0; r < 4; ++r) {
        pv[r] += __shfl_xor(pv[r], 1, 64);
        pv[r] += __shfl_xor(pv[r], 2, 64);
        pv[r] += __shfl_xor(pv[r], 4, 64);
        pv[r] += __shfl_xor(pv[r], 8, 64);
        pv[r] += __shfl_xor(pv[r], 16, 64);
    }
    if (gg == 0) {
        #pragma unroll
        for (int r = 0; r < 4; ++r) red[mg][r] = pv[r];
    }
    __syncthreads();
    if (tid < 64) {
        int m = m0 + tid;
        float v = fmaxf(red[tid >> 2][tid & 3] + b2[0], 0.0f);
        int b = m >> lgC, tl = m & (C - 1);
        out[(size_t)b * T_ + t0 + tl] = v;
    }
}

// ---------- GRU recurrence (exact R12 inner loop — best measured) ----------
// tid = 2j+hf. Split: z u0..11 VGPR fp16 | n u0..15 + z u12..14 LDS (19 slabs)
// | r u0..15 fp8 + z u15 streamed (issued at step head, consumed through the dots).
__device__ __forceinline__ void rec_body(const uint32_t* __restrict__ whh,
        const float* __restrict__ bhh, const float* __restrict__ xg,
        f16* __restrict__ hout, float* __restrict__ state,
        int b, int C, char* smem) {
    int tid = threadIdx.x;
    int j = tid >> 1, hf = tid & 1;
    const u32x4* wb = (const u32x4*)whh;              // fp16 planes
    const u32x2* w8 = (const u32x2*)(whh + 65536);    // fp8 r planes
    u32x4* wlds = (u32x4*)smem;                       // 19 slabs x [512]
    u32x4 (*hq)[2][17] = (u32x4(*)[2][17])(smem + 155648);

    // stage slabs thread-major: 0..15 = n (P=16..31), 16..18 = z u12..14
    #pragma unroll
    for (int s = 0; s < 16; ++s)
        wlds[s * 512 + tid] = wb[(16 + s) * 512 + tid];
    #pragma unroll
    for (int s = 0; s < 3; ++s)
        wlds[(16 + s) * 512 + tid] = wb[(12 + s) * 512 + tid];

    // resident z u0..11
    u32x4 Z0  = wb[ 0 * 512 + tid], Z1  = wb[ 1 * 512 + tid];
    u32x4 Z2  = wb[ 2 * 512 + tid], Z3  = wb[ 3 * 512 + tid];
    u32x4 Z4  = wb[ 4 * 512 + tid], Z5  = wb[ 5 * 512 + tid];
    u32x4 Z6  = wb[ 6 * 512 + tid], Z7  = wb[ 7 * 512 + tid];
    u32x4 Z8  = wb[ 8 * 512 + tid], Z9  = wb[ 9 * 512 + tid];
    u32x4 Z10 = wb[10 * 512 + tid], Z11 = wb[11 * 512 + tid];

    float h_old = 0.0f, bhr = 0.0f, bhz = 0.0f, bhn = 0.0f;
    if (hf == 0) {
        h_old = state[b * 256 + j];
        bhr = bhh[j]; bhz = bhh[256 + j]; bhn = bhh[512 + j];
        ((f16*)&hq[0][j >> 7][0])[j & 127] = (f16)h_old;
    }
    __syncthreads();

    const float* xgt = xg + (size_t)b * C * G_;
    f16* hob = hout + (size_t)b * C * H_;
    const u32x4* nl = wlds + tid;

    for (int tl = 0; tl < C; ++tl) {
        int p = tl & 1;
        // issue all streamed loads up-front (16 fp8 pairs + 1 fp16 quad + xg)
        u32x2 F0  = w8[ 0 * 512 + tid], F1  = w8[ 1 * 512 + tid];
        u32x2 F2  = w8[ 2 * 512 + tid], F3  = w8[ 3 * 512 + tid];
        u32x2 F4  = w8[ 4 * 512 + tid], F5  = w8[ 5 * 512 + tid];
        u32x2 F6  = w8[ 6 * 512 + tid], F7  = w8[ 7 * 512 + tid];
        u32x2 F8  = w8[ 8 * 512 + tid], F9  = w8[ 9 * 512 + tid];
        u32x2 F10 = w8[10 * 512 + tid], F11 = w8[11 * 512 + tid];
        u32x2 F12 = w8[12 * 512 + tid], F13 = w8[13 * 512 + tid];
        u32x2 F14 = w8[14 * 512 + tid], F15 = w8[15 * 512 + tid];
        u32x4 SZ = wb[15 * 512 + tid];
        float xr = 0, xz = 0, xn = 0;
        if (hf == 0) { xr = xgt[j]; xz = xgt[256 + j]; xn = xgt[512 + j]; }

        const u32x4* hp = &hq[p][hf][0];
        float aR = 0.0f, aZ = 0.0f, aN = 0.0f;

#define PU(u, ZS) { u32x4 hv = hp[u]; \
        aN = dot_u4(nl[(u) * 512], hv, aN); \
        aZ = dot_u4(ZS, hv, aZ); \
        u32x4 wr; \
        wr.x = __byte_perm(F##u.x, 0u, 0x1404); \
        wr.y = __byte_perm(F##u.x, 0u, 0x3424); \
        wr.z = __byte_perm(F##u.y, 0u, 0x1404); \
        wr.w = __byte_perm(F##u.y, 0u, 0x3424); \
        aR = dot_u4(wr, hv, aR); }

        PU(0,  Z0)  PU(1,  Z1)  PU(2,  Z2)  PU(3,  Z3)
        PU(4,  Z4)  PU(5,  Z5)  PU(6,  Z6)  PU(7,  Z7)
        PU(8,  Z8)  PU(9,  Z9)  PU(10, Z10) PU(11, Z11)
        PU(12, nl[16 * 512]) PU(13, nl[17 * 512]) PU(14, nl[18 * 512])
        PU(15, SZ)
#undef PU

        // combine the two K-halves (adjacent lanes 2j / 2j+1)
        aR += __shfl_xor(aR, 1, 64);
        aZ += __shfl_xor(aZ, 1, 64);
        aN += __shfl_xor(aN, 1, 64);

        if (hf == 0) {
            float r = sigmoid_f(xr + aR + bhr);
            float z = sigmoid_f(xz + aZ + bhz);
            float n = tanh_f(xn + r * (aN + bhn));
            h_old = z * (h_old - n) + n;   // (1-z)*n + z*h
            f16 hh = (f16)h_old;
            hob[(size_t)tl * H_ + j] = hh;
            ((f16*)&hq[p ^ 1][j >> 7][0])[j & 127] = hh;
        }
        __syncthreads();
        xgt += G_;
    }
    if (hf == 0) state[b * 256 + j] = h_old;
}

// =======================================================================
// fused dispatch, depth-3 pipeline:
//   [0,64)          rec0(i)
//   [64,128)        rec1(i-2)
//   [128,128+C)     xg0(i+1)
//   [128+C,128+4C)  xg1(i-1)
//   [128+4C,128+5C) reg(i-3)
// =======================================================================
__global__ __launch_bounds__(512)
__attribute__((amdgpu_waves_per_eu(2, 2)))
void fused_step(int i, int nC, int C, int lgC,
        const float* __restrict__ x,
        const float* __restrict__ wih0, const float* __restrict__ bih0,
        const uint32_t* __restrict__ whh0, const float* __restrict__ bhh0,
        const uint32_t* __restrict__ whh1, const float* __restrict__ bhh1,
        const uint32_t* __restrict__ wih1T, const float* __restrict__ bih1,
        const uint32_t* __restrict__ w1T, const float* __restrict__ b1,
        const float* __restrict__ w2, const float* __restrict__ b2,
        float* __restrict__ xg0a, float* __restrict__ xg0b,
        float* __restrict__ xg1a, float* __restrict__ xg1b,
        f16* __restrict__ h1a, f16* __restrict__ h1b,
        f16* __restrict__ h2a, f16* __restrict__ h2b,
        float* __restrict__ st0, float* __restrict__ st1,
        float* __restrict__ out) {
    extern __shared__ __align__(16) char smem[];
    int blk = blockIdx.x;
    if (blk < 64) {
        if (i >= nC) return;
        rec_body(whh0, bhh0, (i & 1) ? xg0b : xg0a,
                 (i & 1) ? h1b : h1a, st0, blk, C, smem);
    } else if (blk < 128) {
        int c = i - 2;
        if (c < 0 || c >= nC) return;
        rec_body(whh1, bhh1, (c & 1) ? xg1b : xg1a,
                 (c & 1) ? h2b : h2a, st1, blk - 64, C, smem);
    } else if (blk < 128 + C) {
        int c = i + 1;
        if (c >= nC) return;
        xg0_body(x, wih0, bih0, (c & 1) ? xg0b : xg0a, c * C, C, blk - 128, smem);
    } else if (blk < 128 + 4 * C) {
        int c = i - 1;
        if (c < 0 || c >= nC) return;
        xg1_body((c & 1) ? h1b : h1a, wih1T, bih1,
                 (c & 1) ? xg1b : xg1a, C, lgC, blk - 128 - C, smem);
    } else {
        int c = i - 3;
        if (c < 0 || c >= nC) return;
        reg_body((c & 1) ? h2b : h2a, w1T, b1, w2, b2, out, c * C, C, lgC,
                 blk - 128 - 4 * C, smem);
    }
}

// ---------- standalone xg0 (chunk 0 prelaunch) ----------
__global__ __launch_bounds__(512) void xg0_stand(const float* __restrict__ x,
        const float* __restrict__ wih0, const float* __restrict__ bih0,
        float* __restrict__ xg, int t0, int C) {
    __shared__ __align__(16) char smem[4096];
    xg0_body(x, wih0, bih0, xg, t0, C, blockIdx.x, smem);
}

// ---------- host ----------
extern "C" void kernel_launch(void* const* d_in, const int* in_sizes, int n_in,
                              void* d_out, int out_size, void* d_ws, size_t ws_size,
                              hipStream_t stream) {
    const float* x    = (const float*)d_in[0];
    const float* Wih0 = (const float*)d_in[1];
    const float* Whh0 = (const float*)d_in[2];
    const float* bih0 = (const float*)d_in[3];
    const float* bhh0 = (const float*)d_in[4];
    const float* Wih1 = (const float*)d_in[5];
    const float* Whh1 = (const float*)d_in[6];
    const float* bih1 = (const float*)d_in[7];
    const float* bhh1 = (const float*)d_in[8];
    const float* W1   = (const float*)d_in[9];
    const float* b1   = (const float*)d_in[10];
    const float* W2   = (const float*)d_in[11];
    const float* b2   = (const float*)d_in[12];
    float* out = (float*)d_out;

    hipFuncSetAttribute(reinterpret_cast<const void*>(fused_step),
                        hipFuncAttributeMaxDynamicSharedMemorySize, REC_SMEM);

    char* ws = (char*)d_ws;
    uint32_t* wcvt = (uint32_t*)ws;             // 294912 dwords
    const uint32_t* whh0c = wcvt;
    const uint32_t* whh1c = wcvt + 81920;
    const uint32_t* wih1T = wcvt + 163840;
    const uint32_t* w1T   = wcvt + 262144;
    float* state0 = (float*)(ws + 1179648);
    float* state1 = (float*)(ws + 1179648 + 65536);
    size_t fixed = 1179648 + 2 * 65536;

    // per-chunk: xg0 x2 + xg1 x2 (196608C each) + h1 x2 + h2 x2 (32768C each)
    // C=64: 35 dispatches x 64 = 2240 step-slots (vs 2432 at C=128) — fewer
    // serialized step-slots at slightly higher launch/staging overhead.
    int C = 64;
    while (C > 32 && fixed + (size_t)C * 917504 > ws_size) C >>= 1;
    int lgC = 0; while ((1 << lgC) < C) lgC++;
    int nC = T_ / C;

    char* p = ws + fixed;
    float* xg0_buf[2]; float* xg1_buf[2];
    f16* h1_buf[2]; f16* h2_buf[2];
    xg0_buf[0] = (float*)p;  p += (size_t)C * 196608;
    xg0_buf[1] = (float*)p;  p += (size_t)C * 196608;
    xg1_buf[0] = (float*)p;  p += (size_t)C * 196608;
    xg1_buf[1] = (float*)p;  p += (size_t)C * 196608;
    h1_buf[0] = (f16*)p;     p += (size_t)C * 32768;
    h1_buf[1] = (f16*)p;     p += (size_t)C * 32768;
    h2_buf[0] = (f16*)p;     p += (size_t)C * 32768;
    h2_buf[1] = (f16*)p;

    cvt_weights<<<1152, 256, 0, stream>>>(Whh0, Whh1, Wih1, W1, wcvt);
    hipMemsetAsync(state0, 0, 2 * 65536, stream);
    xg0_stand<<<C, 512, 0, stream>>>(x, Wih0, bih0, xg0_buf[0], 0, C);

    for (int i = 0; i <= nC + 2; ++i) {
        fused_step<<<128 + 5 * C, 512, REC_SMEM, stream>>>(i, nC, C, lgC,
            x, Wih0, bih0, whh0c, bhh0, whh1c, bhh1, wih1T, bih1, w1T, b1, W2, b2,
            xg0_buf[0], xg0_buf[1], xg1_buf[0], xg1_buf[1],
            h1_buf[0], h1_buf[1], h2_buf[0], h2_buf[1],
            state0, state1, out);
    }
}